// Round 2
// baseline (164.535 us; speedup 1.0000x reference)
//
#include <hip/hip_runtime.h>
#include <hip/hip_bf16.h>

#define N_NODES 500000
#define N_FEAT 125
#define HID 128
#define OUTD 64
#define N_GRAPHS 4096
#define N_TYPES 100
#define WTILE 32
#define NTILES32 (N_NODES / WTILE)        /* 15625 exact — no tail handling */
#define NBLOCKS 512                        /* 2 blocks/CU now */
#define NWAVES 8
#define WPAD 136    /* bf16 row stride: 16B-aligned; 68 dwords == 4 mod 32 banks */

typedef float f32x4 __attribute__((ext_vector_type(4)));
typedef short s16x8 __attribute__((ext_vector_type(8)));

// LDS layout (bytes) — TABLES ONLY, no per-wave scratch.
// 81472 B/block -> 2 blocks/CU (2*81472 = 162944 <= 163840)
#define OFF_T 0
#define SZ_T (N_TYPES * WPAD * 2)                  // 27200
#define OFF_W2 (OFF_T + SZ_T)                      // 27200
#define OFF_W3 (OFF_W2 + HID * WPAD * 2)           // 62016
#define OFF_B2 (OFF_W3 + OUTD * WPAD * 2)          // 79424
#define OFF_W1 (OFF_B2 + HID * 4)                  // 79936 (W1 pos rows, f32 3x128)
#define LDS_BYTES (OFF_W1 + 3 * HID * 4)           // 81472

// ws layout (bytes)
#define WS_GSUM 0
#define WS_GCNT ((size_t)N_GRAPHS * OUTD * 4)      // 1048576
#define WS_T    (WS_GCNT + (size_t)N_GRAPHS * 4)   // 1064960
#define WS_ZERO WS_T                               // bytes zeroed (gsum+gcnt)
#define WS_ZERO_V4 (WS_ZERO / 16)                  // 66560 f32x4

__device__ __forceinline__ unsigned short f2bf(float f) {
  union { float f; unsigned u; } v; v.f = f;
  unsigned r = v.u + 0x7FFFu + ((v.u >> 16) & 1u);  // RNE
  return (unsigned short)(r >> 16);
}
__device__ __forceinline__ float bf2f(unsigned short u) {
  union { unsigned u; float f; } v; v.u = ((unsigned)u) << 16;
  return v.f;
}
__device__ __forceinline__ unsigned pk2bf(float a, float b) {
  __hip_bfloat162 h = __float22bfloat162_rn(float2{a, b});   // .x -> low 16, .y -> high 16
  union { __hip_bfloat162 h; unsigned u; } v; v.h = h;
  return v.u;
}

// ---- pre-pass: T[100][128] = emb @ W1[3:,:] + b1 (fp32) + zero gsum/gcnt ----
extern "C" __global__ void gnn_prep(const float* __restrict__ emb,
                                    const float* __restrict__ W1,
                                    const float* __restrict__ b1,
                                    unsigned short* __restrict__ Tg,
                                    f32x4* __restrict__ wsz)
{
  const int j = threadIdx.x;                       // 256 blocks x 128 threads
  // folded memset of gsum+gcnt (removes one dispatch from the graph)
  const int tid = blockIdx.x * 128 + j;
  for (int i = tid; i < WS_ZERO_V4; i += 256 * 128)
    wsz[i] = (f32x4){0.f, 0.f, 0.f, 0.f};
  const int g = blockIdx.x;
  if (g < N_TYPES) {
    float acc = b1[j];
    const float* er = emb + g * N_FEAT;
    for (int k = 0; k < N_FEAT; ++k)
      acc = fmaf(er[k], W1[(3 + k) * HID + j], acc);   // W1 read coalesced over j
    Tg[g * HID + j] = f2bf(acc);
  }
}

extern "C" __global__ void __launch_bounds__(512, 4)   /* 4 waves/EU -> 2 blocks/CU */
gnn_main(const float* __restrict__ pos, const int* __restrict__ z,
         const int* __restrict__ batch, const unsigned short* __restrict__ Tg,
         const float* __restrict__ W1, const float* __restrict__ W2,
         const float* __restrict__ b2, const float* __restrict__ W3,
         float* __restrict__ gsum, int* __restrict__ gcnt)
{
  extern __shared__ char lds[];
  unsigned short* Tl  = (unsigned short*)(lds + OFF_T);
  unsigned short* w2t = (unsigned short*)(lds + OFF_W2);
  unsigned short* w3t = (unsigned short*)(lds + OFF_W3);
  float* bias2 = (float*)(lds + OFF_B2);
  float* w1l   = (float*)(lds + OFF_W1);

  const int t = threadIdx.x;

  // ---- stage once per block ----
  for (int i = t; i < N_TYPES * HID; i += 512) {   // T: bf16, padded rows
    int g = i >> 7, f = i & 127;
    Tl[g * WPAD + f] = Tg[i];
  }
  for (int i = t; i < HID * HID; i += 512) {       // W2^T [n][k] bf16
    int k = i >> 7, n = i & 127;
    w2t[n * WPAD + k] = f2bf(W2[i]);
  }
  for (int i = t; i < HID * OUTD; i += 512) {      // W3^T [n][k] bf16
    int k = i >> 6, n = i & 63;
    w3t[n * WPAD + k] = f2bf(W3[i]);
  }
  if (t < HID) bias2[t] = b2[t];
  if (t < 3 * HID) w1l[t] = W1[t];                 // pos rows of W1, f32

  const int wave = t >> 6, lane = t & 63, quad = lane >> 4, l15 = lane & 15;
  const bool hi32 = (lane >= 32);
  // bpermute pull addresses for the C->B fragment transpose (tile-invariant):
  // src lane = 16*(2*(q&1) + (j2>>1)) + l15
  const int A0 = ((((lane >> 4) & 1) << 5) + l15) << 2;
  const int A1 = A0 + 64;

  __syncthreads();   // the ONLY block-wide barrier

  const int gwave = blockIdx.x * NWAVES + wave;

  for (int tile = gwave; tile < NTILES32; tile += NBLOCKS * NWAVES) {
    const int base = tile * WTILE;

    // per-column graph ids for the in-register pool (quads duplicate, cache-broadcast)
    const int id0 = batch[base + l15];
    const int id1 = batch[base + 16 + l15];

    // ---- layer 1 in VALU, directly into MFMA B-fragments (x^T operand) ----
    // h1[node][f] = relu(T[z][f] + px*W1r0[f] + py*W1r1[f] + pz*W1r2[f])
    float px[2], py[2], pz[2];
    const unsigned short* Tr[2];
    #pragma unroll
    for (int m = 0; m < 2; ++m) {
      const int node = base + m * 16 + l15;        // always < N_NODES (exact tiles)
      const int zi = z[node];
      px[m] = pos[node * 3]; py[m] = pos[node * 3 + 1]; pz[m] = pos[node * 3 + 2];
      Tr[m] = Tl + zi * WPAD;
    }
    s16x8 a[2][4];
    #pragma unroll
    for (int k = 0; k < 4; ++k) {
      // W1 pos-row slice for this k (broadcast within quads, conflict-free)
      float w1s[3][8];
      #pragma unroll
      for (int c = 0; c < 3; ++c) {
        *(f32x4*)&w1s[c][0] = *(const f32x4*)(w1l + c * HID + k * 32 + quad * 8);
        *(f32x4*)&w1s[c][4] = *(const f32x4*)(w1l + c * HID + k * 32 + quad * 8 + 4);
      }
      #pragma unroll
      for (int m = 0; m < 2; ++m) {
        s16x8 tf = *(const s16x8*)(Tr[m] + k * 32 + quad * 8);
        s16x8 fr;
        #pragma unroll
        for (int j = 0; j < 8; j += 2) {
          float v0 = bf2f((unsigned short)tf[j])
                   + px[m] * w1s[0][j] + py[m] * w1s[1][j] + pz[m] * w1s[2][j];
          float v1 = bf2f((unsigned short)tf[j + 1])
                   + px[m] * w1s[0][j + 1] + py[m] * w1s[1][j + 1] + pz[m] * w1s[2][j + 1];
          ((unsigned*)&fr)[j >> 1] = pk2bf(fmaxf(v0, 0.f), fmaxf(v1, 0.f));
        }
        a[m][k] = fr;
      }
    }

    // ---- layer 2: D = W2^T(A) x h1^T(B) -> C: row=out-feature, col=node ----
    f32x4 acc[8][2] = {};
    __builtin_amdgcn_s_setprio(1);
    #pragma unroll
    for (int oi = 0; oi < 8; ++oi)
      #pragma unroll
      for (int k = 0; k < 4; ++k) {
        s16x8 w = *(const s16x8*)(w2t + (oi * 16 + l15) * WPAD + k * 32 + quad * 8);
        acc[oi][0] = __builtin_amdgcn_mfma_f32_16x16x32_bf16(w, a[0][k], acc[oi][0], 0, 0, 0);
        acc[oi][1] = __builtin_amdgcn_mfma_f32_16x16x32_bf16(w, a[1][k], acc[oi][1], 0, 0, 0);
      }
    __builtin_amdgcn_s_setprio(0);

    // ---- epilogue 2: bias+relu+pack, h2 stays IN REGISTERS (no LDS scratch) ----
    // P[oi][m].d_i @(q,l15) = bf16 pair of features {oi*16+q*4+2i, +1} of node m*16+l15
    unsigned P[8][2][2];
    #pragma unroll
    for (int oi = 0; oi < 8; ++oi) {
      const int f0 = oi * 16 + quad * 4;
      f32x4 bv = *(const f32x4*)(bias2 + f0);
      #pragma unroll
      for (int m = 0; m < 2; ++m) {
        P[oi][m][0] = pk2bf(fmaxf(acc[oi][m][0] + bv[0], 0.f),
                            fmaxf(acc[oi][m][1] + bv[1], 0.f));
        P[oi][m][1] = pk2bf(fmaxf(acc[oi][m][2] + bv[2], 0.f),
                            fmaxf(acc[oi][m][3] + bv[3], 0.f));
      }
    }

    // ---- C-layout -> B-fragment transpose via ds_bpermute (pure lane perm) ----
    // a[m][kb].dw[j2] = P[2kb+(q>>1)][m].d(j2&1) from lane (quad 2(q&1)+(j2>>1), l15)
    #pragma unroll
    for (int m = 0; m < 2; ++m)
      #pragma unroll
      for (int kb = 0; kb < 4; ++kb) {
        s16x8 fr;
        #pragma unroll
        for (int j2 = 0; j2 < 4; ++j2) {
          const int addr = (j2 < 2) ? A0 : A1;
          int t0 = __builtin_amdgcn_ds_bpermute(addr, (int)P[2 * kb][m][j2 & 1]);
          int t1 = __builtin_amdgcn_ds_bpermute(addr, (int)P[2 * kb + 1][m][j2 & 1]);
          ((int*)&fr)[j2] = hi32 ? t1 : t0;
        }
        a[m][kb] = fr;
      }

    // ---- layer 3: D = W3^T x h2^T -> row=out-dim, col=node; b3 folded into finalize
    f32x4 acc3[4][2] = {};
    __builtin_amdgcn_s_setprio(1);
    #pragma unroll
    for (int oi = 0; oi < 4; ++oi)
      #pragma unroll
      for (int k = 0; k < 4; ++k) {
        s16x8 w = *(const s16x8*)(w3t + (oi * 16 + l15) * WPAD + k * 32 + quad * 8);
        acc3[oi][0] = __builtin_amdgcn_mfma_f32_16x16x32_bf16(w, a[0][k], acc3[oi][0], 0, 0, 0);
        acc3[oi][1] = __builtin_amdgcn_mfma_f32_16x16x32_bf16(w, a[1][k], acc3[oi][1], 0, 0, 0);
      }
    __builtin_amdgcn_s_setprio(0);

    // ---- pool: in-register segmented reduce (batch sorted; avg 1.26 runs/tile)
    // acc3 layout: col(node)=l15 (+16*m), row(out-dim)=oi*16+quad*4+r.
    {
      int done = 0;
      while (done < 32) {                          // wave-uniform loop
        // run id from registers (no dependent global load): ids live in id0/id1
        const int srcv = (done < 16) ? id0 : id1;
        const int g = __builtin_amdgcn_readlane(srcv, done & 15);
        const bool m0 = (id0 == g), m1 = (id1 == g);
        float red[4][4];
        #pragma unroll
        for (int oi = 0; oi < 4; ++oi)
          #pragma unroll
          for (int r = 0; r < 4; ++r)
            red[oi][r] = (m0 ? acc3[oi][0][r] : 0.f) + (m1 ? acc3[oi][1][r] : 0.f);
        #pragma unroll
        for (int s = 1; s <= 8; s <<= 1)
          #pragma unroll
          for (int oi = 0; oi < 4; ++oi)
            #pragma unroll
            for (int r = 0; r < 4; ++r)
              red[oi][r] += __shfl_xor(red[oi][r], s, 64);
        const int cnt = (int)((__popcll(__ballot(m0)) + __popcll(__ballot(m1))) >> 2);
        if (l15 == 0) {                            // 4 lanes (one per quad) fire atomics
          #pragma unroll
          for (int oi = 0; oi < 4; ++oi)
            #pragma unroll
            for (int r = 0; r < 4; ++r)
              atomicAdd(&gsum[g * OUTD + oi * 16 + quad * 4 + r], red[oi][r]);
        }
        if (lane == 0) atomicAdd(&gcnt[g], cnt);
        done += cnt;                               // cnt >= 1: column `done` matches g
      }
    }
  }
}

extern "C" __global__ void gnn_finalize(const float* __restrict__ gsum,
                                        const int* __restrict__ gcnt,
                                        const float* __restrict__ b3,
                                        float* __restrict__ out)
{
  int i = blockIdx.x * 256 + threadIdx.x;
  if (i < N_GRAPHS * OUTD) {
    int g = i >> 6, o = i & 63;
    int c = gcnt[g];
    out[i] = (c > 0) ? (gsum[i] / (float)c + b3[o]) : 0.f;
  }
}

extern "C" void kernel_launch(void* const* d_in, const int* in_sizes, int n_in,
                              void* d_out, int out_size, void* d_ws, size_t ws_size,
                              hipStream_t stream) {
  const float* pos  = (const float*)d_in[0];
  const int*   z    = (const int*)d_in[1];
  const int*   batch= (const int*)d_in[2];
  const float* emb  = (const float*)d_in[3];
  const float* W1   = (const float*)d_in[4];
  const float* b1   = (const float*)d_in[5];
  const float* W2   = (const float*)d_in[6];
  const float* b2   = (const float*)d_in[7];
  const float* W3   = (const float*)d_in[8];
  const float* b3   = (const float*)d_in[9];

  float* gsum = (float*)d_ws;
  int*   gcnt = (int*)((char*)d_ws + WS_GCNT);
  unsigned short* Tg = (unsigned short*)((char*)d_ws + WS_T);

  // prep also zeroes gsum/gcnt (memset dispatch folded in)
  hipLaunchKernelGGL(gnn_prep, dim3(256), dim3(HID), 0, stream,
                     emb, W1, b1, Tg, (f32x4*)d_ws);

  hipFuncSetAttribute((const void*)gnn_main,
                      hipFuncAttributeMaxDynamicSharedMemorySize, LDS_BYTES);
  hipLaunchKernelGGL(gnn_main, dim3(NBLOCKS), dim3(512), LDS_BYTES, stream,
                     pos, z, batch, Tg, W1, W2, b2, W3, gsum, gcnt);
  hipLaunchKernelGGL(gnn_finalize, dim3((N_GRAPHS * OUTD + 255) / 256), dim3(256), 0, stream,
                     gsum, gcnt, b3, (float*)d_out);
}

// Round 3
// 160.928 us; speedup vs baseline: 1.0224x; 1.0224x over previous
//
#include <hip/hip_runtime.h>
#include <hip/hip_bf16.h>

#define N_NODES 500000
#define N_FEAT 125
#define HID 128
#define OUTD 64
#define N_GRAPHS 4096
#define N_TYPES 100
#define WTILE 32
#define NTILES32 (N_NODES / WTILE)        /* 15625 exact — no tail handling */
#define NBLOCKS 512                        /* 2 blocks/CU */
#define NWAVES 8
#define WPAD 136    /* bf16 row stride: 16B-aligned; 68 dwords == 4 mod 32 banks */

typedef float f32x4 __attribute__((ext_vector_type(4)));
typedef short s16x8 __attribute__((ext_vector_type(8)));

// LDS layout (bytes) — TABLES ONLY, no per-wave scratch.
// 81472 B/block -> 2 blocks/CU (2*81472 = 162944 <= 163840)
#define OFF_T 0
#define SZ_T (N_TYPES * WPAD * 2)                  // 27200
#define OFF_W2 (OFF_T + SZ_T)                      // 27200
#define OFF_W3 (OFF_W2 + HID * WPAD * 2)           // 62016
#define OFF_B2 (OFF_W3 + OUTD * WPAD * 2)          // 79424
#define OFF_W1 (OFF_B2 + HID * 4)                  // 79936 (W1 pos rows, f32 3x128)
#define LDS_BYTES (OFF_W1 + 3 * HID * 4)           // 81472

// ws layout (bytes)
#define WS_GSUM 0
#define WS_GCNT ((size_t)N_GRAPHS * OUTD * 4)      // 1048576
#define WS_T    (WS_GCNT + (size_t)N_GRAPHS * 4)   // 1064960
#define WS_ZERO WS_T                               // bytes zeroed (gsum+gcnt)
#define WS_ZERO_V4 (WS_ZERO / 16)                  // 66560 f32x4

__device__ __forceinline__ unsigned short f2bf(float f) {
  union { float f; unsigned u; } v; v.f = f;
  unsigned r = v.u + 0x7FFFu + ((v.u >> 16) & 1u);  // RNE
  return (unsigned short)(r >> 16);
}
__device__ __forceinline__ float bf2f(unsigned short u) {
  union { unsigned u; float f; } v; v.u = ((unsigned)u) << 16;
  return v.f;
}
__device__ __forceinline__ unsigned pk2bf(float a, float b) {
  __hip_bfloat162 h = __float22bfloat162_rn(float2{a, b});   // .x -> low 16, .y -> high 16
  union { __hip_bfloat162 h; unsigned u; } v; v.h = h;
  return v.u;
}

// ---- pre-pass: T[100][128] = emb @ W1[3:,:] + b1 (fp32) + zero gsum/gcnt ----
extern "C" __global__ void gnn_prep(const float* __restrict__ emb,
                                    const float* __restrict__ W1,
                                    const float* __restrict__ b1,
                                    unsigned short* __restrict__ Tg,
                                    f32x4* __restrict__ wsz)
{
  const int j = threadIdx.x;                       // 256 blocks x 128 threads
  // folded memset of gsum+gcnt (removes one dispatch from the graph)
  const int tid = blockIdx.x * 128 + j;
  for (int i = tid; i < WS_ZERO_V4; i += 256 * 128)
    wsz[i] = (f32x4){0.f, 0.f, 0.f, 0.f};
  const int g = blockIdx.x;
  if (g < N_TYPES) {
    float acc = b1[j];
    const float* er = emb + g * N_FEAT;
    for (int k = 0; k < N_FEAT; ++k)
      acc = fmaf(er[k], W1[(3 + k) * HID + j], acc);   // W1 read coalesced over j
    Tg[g * HID + j] = f2bf(acc);
  }
}

extern "C" __global__ void __launch_bounds__(512, 4)   /* 4 waves/EU -> 2 blocks/CU */
gnn_main(const float* __restrict__ pos, const int* __restrict__ z,
         const int* __restrict__ batch, const unsigned short* __restrict__ Tg,
         const float* __restrict__ W1, const float* __restrict__ W2,
         const float* __restrict__ b2, const float* __restrict__ W3,
         float* __restrict__ gsum, int* __restrict__ gcnt)
{
  extern __shared__ char lds[];
  unsigned short* Tl  = (unsigned short*)(lds + OFF_T);
  unsigned short* w2t = (unsigned short*)(lds + OFF_W2);
  unsigned short* w3t = (unsigned short*)(lds + OFF_W3);
  float* bias2 = (float*)(lds + OFF_B2);
  float* w1l   = (float*)(lds + OFF_W1);

  const int t = threadIdx.x;

  // ---- stage once per block ----
  for (int i = t; i < N_TYPES * HID; i += 512) {   // T: bf16, padded rows
    int g = i >> 7, f = i & 127;
    Tl[g * WPAD + f] = Tg[i];
  }
  for (int i = t; i < HID * HID; i += 512) {       // W2^T [n][k] bf16
    int k = i >> 7, n = i & 127;
    w2t[n * WPAD + k] = f2bf(W2[i]);
  }
  for (int i = t; i < HID * OUTD; i += 512) {      // W3^T [n][k] bf16
    int k = i >> 6, n = i & 63;
    w3t[n * WPAD + k] = f2bf(W3[i]);
  }
  if (t < HID) bias2[t] = b2[t];
  if (t < 3 * HID) w1l[t] = W1[t];                 // pos rows of W1, f32

  const int wave = t >> 6, lane = t & 63, quad = lane >> 4, l15 = lane & 15;
  const bool hi32 = (lane >= 32);
  // bpermute pull addresses for the C->B fragment transpose (tile-invariant):
  // src lane = 16*(2*(q&1) + (j2>>1)) + l15
  const int A0 = ((((lane >> 4) & 1) << 5) + l15) << 2;
  const int A1 = A0 + 64;

  __syncthreads();   // the ONLY block-wide barrier

  const int gwave = blockIdx.x * NWAVES + wave;

  for (int tile = gwave; tile < NTILES32; tile += NBLOCKS * NWAVES) {
    const int base = tile * WTILE;

    // per-column graph ids for the in-register pool (quads duplicate, cache-broadcast)
    const int id0 = batch[base + l15];
    const int id1 = batch[base + 16 + l15];

    // ---- layer 1 in VALU, directly into MFMA B-fragments (x^T operand) ----
    // h1[node][f] = relu(T[z][f] + px*W1r0[f] + py*W1r1[f] + pz*W1r2[f])
    float px[2], py[2], pz[2];
    const unsigned short* Tr[2];
    #pragma unroll
    for (int m = 0; m < 2; ++m) {
      const int node = base + m * 16 + l15;        // always < N_NODES (exact tiles)
      const int zi = z[node];
      px[m] = pos[node * 3]; py[m] = pos[node * 3 + 1]; pz[m] = pos[node * 3 + 2];
      Tr[m] = Tl + zi * WPAD;
    }
    s16x8 a[2][4];
    #pragma unroll
    for (int k = 0; k < 4; ++k) {
      // W1 pos-row slice for this k (broadcast within quads, conflict-free)
      float w1s[3][8];
      #pragma unroll
      for (int c = 0; c < 3; ++c) {
        *(f32x4*)&w1s[c][0] = *(const f32x4*)(w1l + c * HID + k * 32 + quad * 8);
        *(f32x4*)&w1s[c][4] = *(const f32x4*)(w1l + c * HID + k * 32 + quad * 8 + 4);
      }
      #pragma unroll
      for (int m = 0; m < 2; ++m) {
        s16x8 tf = *(const s16x8*)(Tr[m] + k * 32 + quad * 8);
        s16x8 fr;
        #pragma unroll
        for (int j = 0; j < 8; j += 2) {
          float v0 = bf2f((unsigned short)tf[j])
                   + px[m] * w1s[0][j] + py[m] * w1s[1][j] + pz[m] * w1s[2][j];
          float v1 = bf2f((unsigned short)tf[j + 1])
                   + px[m] * w1s[0][j + 1] + py[m] * w1s[1][j + 1] + pz[m] * w1s[2][j + 1];
          ((unsigned*)&fr)[j >> 1] = pk2bf(fmaxf(v0, 0.f), fmaxf(v1, 0.f));
        }
        a[m][k] = fr;
      }
    }

    // ---- layer 2 + fused epilogue, one 16-row strip (oi) at a time ----
    // Only ONE accumulator pair (8 regs) live instead of acc[8][2] (64 regs):
    // peak pressure ~110 regs -> fits the 128-reg cap of 4 waves/SIMD w/o spill.
    // P[oi][m].d_i @(q,l15) = bf16 pair of features {oi*16+q*4+2i,+1} of node m*16+l15
    unsigned P[8][2][2];
    __builtin_amdgcn_s_setprio(1);
    #pragma unroll
    for (int oi = 0; oi < 8; ++oi) {
      f32x4 c0 = {}, c1 = {};
      #pragma unroll
      for (int k = 0; k < 4; ++k) {
        s16x8 w = *(const s16x8*)(w2t + (oi * 16 + l15) * WPAD + k * 32 + quad * 8);
        c0 = __builtin_amdgcn_mfma_f32_16x16x32_bf16(w, a[0][k], c0, 0, 0, 0);
        c1 = __builtin_amdgcn_mfma_f32_16x16x32_bf16(w, a[1][k], c1, 0, 0, 0);
      }
      const int f0 = oi * 16 + quad * 4;
      f32x4 bv = *(const f32x4*)(bias2 + f0);
      P[oi][0][0] = pk2bf(fmaxf(c0[0] + bv[0], 0.f), fmaxf(c0[1] + bv[1], 0.f));
      P[oi][0][1] = pk2bf(fmaxf(c0[2] + bv[2], 0.f), fmaxf(c0[3] + bv[3], 0.f));
      P[oi][1][0] = pk2bf(fmaxf(c1[0] + bv[0], 0.f), fmaxf(c1[1] + bv[1], 0.f));
      P[oi][1][1] = pk2bf(fmaxf(c1[2] + bv[2], 0.f), fmaxf(c1[3] + bv[3], 0.f));
    }
    __builtin_amdgcn_s_setprio(0);

    // ---- C-layout -> B-fragment transpose via ds_bpermute (pure lane perm) ----
    // a[m][kb].dw[j2] = P[2kb+(q>>1)][m].d(j2&1) from lane (quad 2(q&1)+(j2>>1), l15)
    #pragma unroll
    for (int m = 0; m < 2; ++m)
      #pragma unroll
      for (int kb = 0; kb < 4; ++kb) {
        s16x8 fr;
        #pragma unroll
        for (int j2 = 0; j2 < 4; ++j2) {
          const int addr = (j2 < 2) ? A0 : A1;
          int t0 = __builtin_amdgcn_ds_bpermute(addr, (int)P[2 * kb][m][j2 & 1]);
          int t1 = __builtin_amdgcn_ds_bpermute(addr, (int)P[2 * kb + 1][m][j2 & 1]);
          ((int*)&fr)[j2] = hi32 ? t1 : t0;
        }
        a[m][kb] = fr;
      }

    // ---- layer 3: D = W3^T x h2^T -> row=out-dim, col=node; b3 folded into finalize
    f32x4 acc3[4][2] = {};
    __builtin_amdgcn_s_setprio(1);
    #pragma unroll
    for (int oi = 0; oi < 4; ++oi)
      #pragma unroll
      for (int k = 0; k < 4; ++k) {
        s16x8 w = *(const s16x8*)(w3t + (oi * 16 + l15) * WPAD + k * 32 + quad * 8);
        acc3[oi][0] = __builtin_amdgcn_mfma_f32_16x16x32_bf16(w, a[0][k], acc3[oi][0], 0, 0, 0);
        acc3[oi][1] = __builtin_amdgcn_mfma_f32_16x16x32_bf16(w, a[1][k], acc3[oi][1], 0, 0, 0);
      }
    __builtin_amdgcn_s_setprio(0);

    // ---- pool: in-register segmented reduce (batch sorted; avg 1.26 runs/tile)
    // acc3 layout: col(node)=l15 (+16*m), row(out-dim)=oi*16+quad*4+r.
    {
      int done = 0;
      while (done < 32) {                          // wave-uniform loop
        // run id from registers (no dependent global load): ids live in id0/id1
        const int srcv = (done < 16) ? id0 : id1;
        const int g = __builtin_amdgcn_readlane(srcv, done & 15);
        const bool m0 = (id0 == g), m1 = (id1 == g);
        float red[4][4];
        #pragma unroll
        for (int oi = 0; oi < 4; ++oi)
          #pragma unroll
          for (int r = 0; r < 4; ++r)
            red[oi][r] = (m0 ? acc3[oi][0][r] : 0.f) + (m1 ? acc3[oi][1][r] : 0.f);
        #pragma unroll
        for (int s = 1; s <= 8; s <<= 1)
          #pragma unroll
          for (int oi = 0; oi < 4; ++oi)
            #pragma unroll
            for (int r = 0; r < 4; ++r)
              red[oi][r] += __shfl_xor(red[oi][r], s, 64);
        const int cnt = (int)((__popcll(__ballot(m0)) + __popcll(__ballot(m1))) >> 2);
        if (l15 == 0) {                            // 4 lanes (one per quad) fire atomics
          #pragma unroll
          for (int oi = 0; oi < 4; ++oi)
            #pragma unroll
            for (int r = 0; r < 4; ++r)
              atomicAdd(&gsum[g * OUTD + oi * 16 + quad * 4 + r], red[oi][r]);
        }
        if (lane == 0) atomicAdd(&gcnt[g], cnt);
        done += cnt;                               // cnt >= 1: column `done` matches g
      }
    }
  }
}

extern "C" __global__ void gnn_finalize(const float* __restrict__ gsum,
                                        const int* __restrict__ gcnt,
                                        const float* __restrict__ b3,
                                        float* __restrict__ out)
{
  int i = blockIdx.x * 256 + threadIdx.x;
  if (i < N_GRAPHS * OUTD) {
    int g = i >> 6, o = i & 63;
    int c = gcnt[g];
    out[i] = (c > 0) ? (gsum[i] / (float)c + b3[o]) : 0.f;
  }
}

extern "C" void kernel_launch(void* const* d_in, const int* in_sizes, int n_in,
                              void* d_out, int out_size, void* d_ws, size_t ws_size,
                              hipStream_t stream) {
  const float* pos  = (const float*)d_in[0];
  const int*   z    = (const int*)d_in[1];
  const int*   batch= (const int*)d_in[2];
  const float* emb  = (const float*)d_in[3];
  const float* W1   = (const float*)d_in[4];
  const float* b1   = (const float*)d_in[5];
  const float* W2   = (const float*)d_in[6];
  const float* b2   = (const float*)d_in[7];
  const float* W3   = (const float*)d_in[8];
  const float* b3   = (const float*)d_in[9];

  float* gsum = (float*)d_ws;
  int*   gcnt = (int*)((char*)d_ws + WS_GCNT);
  unsigned short* Tg = (unsigned short*)((char*)d_ws + WS_T);

  // prep also zeroes gsum/gcnt (memset dispatch folded in)
  hipLaunchKernelGGL(gnn_prep, dim3(256), dim3(HID), 0, stream,
                     emb, W1, b1, Tg, (f32x4*)d_ws);

  hipFuncSetAttribute((const void*)gnn_main,
                      hipFuncAttributeMaxDynamicSharedMemorySize, LDS_BYTES);
  hipLaunchKernelGGL(gnn_main, dim3(NBLOCKS), dim3(512), LDS_BYTES, stream,
                     pos, z, batch, Tg, W1, W2, b2, W3, gsum, gcnt);
  hipLaunchKernelGGL(gnn_finalize, dim3((N_GRAPHS * OUTD + 255) / 256), dim3(256), 0, stream,
                     gsum, gcnt, b3, (float*)d_out);
}